// Round 9
// baseline (2203.113 us; speedup 1.0000x reference)
//
#include <hip/hip_runtime.h>

// ---------------------------------------------------------------------------
// GCN block: 3x (MFMA bf16 GEMM -> degree-normalized aggregate), resid, relu.
// 9 dispatches: memset(cursors) | scatter(fixed-CAP buckets) | dinv(hist) |
//   gemm1 | agg1 | gemm64 | agg2 | gemm64 | agg3
// R21: SORT DELETED. Agg is edge-parallel with LDS f32 accumulation:
// one block per 128-node bucket, streams its UNSORTED packed edges
// (coalesced), gathers hs rows (same 2 lines/edge as the proven ~43us
// node-walk floor -- R16-R20 showed gathers invariant to all structure),
// atomicAdds into a 36.9KB LDS tile. k_sort's only remaining product (deg)
// comes from tiny k_dinv (bucket hist -> rsqrt). LDS layout: feature f of
// row r at acc[r*72 + (f&7)*8 + (f>>3)] -- banks (dl%4)*8+c8 = 2 lanes/bank
// = conflict-free (naive layout would be 16-way). No per-node chains, no
// padding, no col/rp2. NOT fusing per-node deg atomics into scatter (R15's
// hidden k_deg cost: 1.6M global atomics).
// R20: agg gather floor ~43.5us invariant to concurrency/width/traffic.
// R16: single-pass scatter. R15 lesson: random 4B global writes = 104MB
// write amp (here: LDS accum + dense epilogue). R9: dinv in GEMM epilogue.
// ---------------------------------------------------------------------------

#define LB 7
#define BKN 128                    // nodes per bucket
#define CHUNK 4096
#define EPT 16                     // edges per thread in scatter (CHUNK/256)
#define CAP 4096                   // packed slots per bucket (mean fill 2046)

typedef unsigned short ushort_t;
typedef __attribute__((ext_vector_type(8))) short bf16x8;
typedef __attribute__((ext_vector_type(4))) float f32x4;

__device__ __forceinline__ unsigned f2bf(float f) {
    unsigned u = __builtin_bit_cast(unsigned, f);
    return (u + 0x7FFFu + ((u >> 16) & 1u)) >> 16;   // RNE
}
__device__ __forceinline__ float bflo(unsigned u) {
    return __builtin_bit_cast(float, u << 16);
}
__device__ __forceinline__ float bfhi(unsigned u) {
    return __builtin_bit_cast(float, u & 0xFFFF0000u);
}

// per-block int64-vs-int32 probe (sampled; same result in every block)
__device__ int detect_f64(const int* ei, int E, int* sflag) {
    if (threadIdx.x == 0) *sflag = 0;
    __syncthreads();
    const unsigned* raw = (const unsigned*)ei;
    int dwords = min(2 * E, 512);
    int any = 0;
    for (int i = threadIdx.x; i < dwords; i += blockDim.x)
        if ((i & 1) && raw[i]) any = 1;
    if (any) atomicOr(sflag, 1);
    __syncthreads();
    return !*sflag;   // all sampled high words zero => int64
}

// ---- scatter: partition edges into fixed-CAP bucket regions ---------------
// packed[b*CAP + cursor] = (src<<7 | dst&127); cursor is RELATIVE (0-init).
// Single pass over ei: each thread keeps its EPT edges in (unrolled) regs.
__global__ __launch_bounds__(256) void k_scatter(
        const int* __restrict__ ei, int E,
        int* __restrict__ bucketCursor, unsigned int* __restrict__ packed) {
    __shared__ int hist[1024];
    __shared__ int base[1024];
    __shared__ int sflag;
    int f64 = detect_f64(ei, E, &sflag);
    int b0 = blockIdx.x * CHUNK;
    int n = min(CHUNK, E - b0);
    int tid = threadIdx.x;
    for (int i = tid; i < 1024; i += 256) hist[i] = 0;
    __syncthreads();
    int dreg[EPT], sreg[EPT];
#pragma unroll
    for (int i = 0; i < EPT; i++) {
        int idx = tid + i * 256;
        if (idx < n) {
            int e = b0 + idx;
            dreg[i] = f64 ? ei[2 * (E + e)] : ei[E + e];
            sreg[i] = f64 ? ei[2 * e] : ei[e];
            atomicAdd(&hist[dreg[i] >> LB], 1);
        }
    }
    __syncthreads();
    for (int i = tid; i < 1024; i += 256) {
        int c = hist[i];
        base[i] = c ? atomicAdd(&bucketCursor[i], c) : 0;
        hist[i] = 0;
    }
    __syncthreads();
#pragma unroll
    for (int i = 0; i < EPT; i++) {
        int idx = tid + i * 256;
        if (idx < n) {
            int bk = dreg[i] >> LB;
            int pos = bk * CAP + base[bk] + atomicAdd(&hist[bk], 1);
            packed[pos] = ((unsigned)sreg[i] << LB) | (unsigned)(dreg[i] & (BKN - 1));
        }
    }
}

// ---- dinv: per-bucket degree hist -> dinv = rsqrt(deg+1); zero hs row N ----
__global__ __launch_bounds__(256) void k_dinv(
        const unsigned int* __restrict__ packed, const int* __restrict__ bucketCursor,
        float* __restrict__ dinv, ushort_t* __restrict__ hs, int N) {
    __shared__ int hist[BKN];
    int tid = threadIdx.x;
    int b = blockIdx.x;
    if (tid < BKN) hist[tid] = 0;
    __syncthreads();
    int start = b * CAP;
    int end = start + bucketCursor[b];
    for (int e = start + tid; e < end; e += 256)
        atomicAdd(&hist[packed[e] & (BKN - 1)], 1);
    __syncthreads();
    int node = (b << LB) + tid;
    if (tid < BKN && node < N)
        dinv[node] = rsqrtf((float)(hist[tid] + 1));   // +1 self loop
    if (b == 0 && tid < 64) hs[(size_t)N * 64 + tid] = 0;   // zero sentinel row
}

// ---- gemm1: (N x 128) @ (128 x 64), f32 in, dinv-scaled, bf16 out ---------
__global__ __launch_bounds__(256) void k_gemm1(
        const float* __restrict__ A, const float* __restrict__ W,
        const float* __restrict__ dinv, ushort_t* __restrict__ out, int nrows) {
    const int K = 128;
    __shared__ ushort_t sWT[64 * (K + 8)];
    int tid = threadIdx.x;
    for (int i = tid; i < K * 64; i += 256) {
        int n = i & 63, k = i >> 6;
        sWT[n * (K + 8) + k] = (ushort_t)f2bf(W[i]);
    }
    __syncthreads();
    int wave = tid >> 6, lane = tid & 63;
    int quad = lane >> 4, l16 = lane & 15;
    int rowBase = blockIdx.x * 128 + wave * 32;
    f32x4 acc[2][4];
#pragma unroll
    for (int r = 0; r < 2; r++)
#pragma unroll
        for (int c = 0; c < 4; c++) acc[r][c] = (f32x4){0.f, 0.f, 0.f, 0.f};
#pragma unroll
    for (int chunk = 0; chunk < K / 32; chunk++) {
        bf16x8 afr[2];
#pragma unroll
        for (int r = 0; r < 2; r++) {
            int row = rowBase + r * 16 + l16;
            if (row >= nrows) row = nrows - 1;
            const float* ap = A + (size_t)row * K + chunk * 32 + quad * 8;
            float4 v0 = *(const float4*)ap;
            float4 v1 = *(const float4*)(ap + 4);
            bf16x8 a;
            a[0] = (short)f2bf(v0.x); a[1] = (short)f2bf(v0.y);
            a[2] = (short)f2bf(v0.z); a[3] = (short)f2bf(v0.w);
            a[4] = (short)f2bf(v1.x); a[5] = (short)f2bf(v1.y);
            a[6] = (short)f2bf(v1.z); a[7] = (short)f2bf(v1.w);
            afr[r] = a;
        }
#pragma unroll
        for (int c = 0; c < 4; c++) {
            bf16x8 bfr = __builtin_bit_cast(
                bf16x8,
                *(const uint4*)&sWT[(c * 16 + l16) * (K + 8) + chunk * 32 + quad * 8]);
#pragma unroll
            for (int r = 0; r < 2; r++)
                acc[r][c] = __builtin_amdgcn_mfma_f32_16x16x32_bf16(
                    afr[r], bfr, acc[r][c], 0, 0, 0);
        }
    }
#pragma unroll
    for (int r = 0; r < 2; r++)
#pragma unroll
        for (int i = 0; i < 4; i++) {
            int row = rowBase + r * 16 + quad * 4 + i;
            if (row < nrows) {
                float sc = dinv[row];
#pragma unroll
                for (int c = 0; c < 4; c++)
                    out[(size_t)row * 64 + c * 16 + l16] =
                        (ushort_t)f2bf(acc[r][c][i] * sc);
            }
        }
}

// ---- gemm64: (N x 64) @ (64 x 64), bf16 in, dinv-scaled, bf16 out ---------
__global__ __launch_bounds__(256) void k_gemm64(
        const ushort_t* __restrict__ A, const float* __restrict__ W,
        const float* __restrict__ dinv, ushort_t* __restrict__ out, int nrows) {
    const int K = 64;
    __shared__ ushort_t sWT[64 * (K + 8)];
    int tid = threadIdx.x;
    for (int i = tid; i < K * 64; i += 256) {
        int n = i & 63, k = i >> 6;
        sWT[n * (K + 8) + k] = (ushort_t)f2bf(W[i]);
    }
    __syncthreads();
    int wave = tid >> 6, lane = tid & 63;
    int quad = lane >> 4, l16 = lane & 15;
    int rowBase = blockIdx.x * 128 + wave * 32;
    f32x4 acc[2][4];
#pragma unroll
    for (int r = 0; r < 2; r++)
#pragma unroll
        for (int c = 0; c < 4; c++) acc[r][c] = (f32x4){0.f, 0.f, 0.f, 0.f};
#pragma unroll
    for (int chunk = 0; chunk < K / 32; chunk++) {
        bf16x8 afr[2];
#pragma unroll
        for (int r = 0; r < 2; r++) {
            int row = rowBase + r * 16 + l16;
            if (row >= nrows) row = nrows - 1;
            const ushort_t* ap = A + (size_t)row * K + chunk * 32 + quad * 8;
            afr[r] = __builtin_bit_cast(bf16x8, *(const uint4*)ap);
        }
#pragma unroll
        for (int c = 0; c < 4; c++) {
            bf16x8 bfr = __builtin_bit_cast(
                bf16x8,
                *(const uint4*)&sWT[(c * 16 + l16) * (K + 8) + chunk * 32 + quad * 8]);
#pragma unroll
            for (int r = 0; r < 2; r++)
                acc[r][c] = __builtin_amdgcn_mfma_f32_16x16x32_bf16(
                    afr[r], bfr, acc[r][c], 0, 0, 0);
        }
    }
#pragma unroll
    for (int r = 0; r < 2; r++)
#pragma unroll
        for (int i = 0; i < 4; i++) {
            int row = rowBase + r * 16 + quad * 4 + i;
            if (row < nrows) {
                float sc = dinv[row];
#pragma unroll
                for (int c = 0; c < 4; c++)
                    out[(size_t)row * 64 + c * 16 + l16] =
                        (ushort_t)f2bf(acc[r][c][i] * sc);
            }
        }
}

// ---- aggregation: edge-parallel, LDS f32 accumulation per bucket ----------
// Block b owns nodes [b*128, b*128+128). LDS acc tile 128 x 72 f32 (36.9KB),
// feature f of row r stored at acc[r*72 + (f&7)*8 + (f>>3)] (transposed
// octets). Lane = g(3b)|c8(3b): edge slot / feature octet. Per iter a wave
// handles 2x8 edges: packed load (coalesced) -> uint4 gather (8 lanes/row,
// same 2 lines/edge as node-walk floor) -> 8 LDS atomicAdds at k*8+c8
// (banks (dl%4)*8+c8: 2 lanes/bank = conflict-free). Masked slots read
// sentinel row N (zeros) and add to row 0 -> harmless. Epilogue: 2 threads
// per row: +self, *dinv, +bias, relu / +resid, dense coalesced writes.
template <int RELU, int F32OUT>
__global__ __launch_bounds__(256) void k_aggbkt(
        const ushort_t* __restrict__ hs, const float* __restrict__ dinv,
        const float* __restrict__ bias, const unsigned int* __restrict__ packed,
        const int* __restrict__ bucketCursor, const ushort_t* __restrict__ residb,
        float* __restrict__ outf, ushort_t* __restrict__ outb, int N) {
    __shared__ float acc[BKN * 72];
    int tid = threadIdx.x;
    int b = blockIdx.x;
    for (int i = tid; i < BKN * 72; i += 256) acc[i] = 0.f;
    __syncthreads();
    int cnt = bucketCursor[b];
    int start = b * CAP;
    int wid = tid >> 6, lane = tid & 63;
    int g = lane >> 3;                   // edge slot 0..7
    int c8 = lane & 7;                   // feature octet: feats c8*8..c8*8+7
    const ushort_t* hsrc = hs + (size_t)c8 * 8;

#define ATOM(ap, u)                                                         \
    atomicAdd((ap) + 0 * 8 + c8, bflo(u.x));                                \
    atomicAdd((ap) + 1 * 8 + c8, bfhi(u.x));                                \
    atomicAdd((ap) + 2 * 8 + c8, bflo(u.y));                                \
    atomicAdd((ap) + 3 * 8 + c8, bfhi(u.y));                                \
    atomicAdd((ap) + 4 * 8 + c8, bflo(u.z));                                \
    atomicAdd((ap) + 5 * 8 + c8, bfhi(u.z));                                \
    atomicAdd((ap) + 6 * 8 + c8, bflo(u.w));                                \
    atomicAdd((ap) + 7 * 8 + c8, bfhi(u.w));

    for (int e0 = wid * 8; e0 < cnt; e0 += 64) {
        int idxA = e0 + g;
        int idxB = e0 + 32 + g;
        unsigned pkA = packed[start + idxA];       // +64 slack guards overread
        unsigned pkB = packed[start + idxB];
        int srcA = (idxA < cnt) ? (int)(pkA >> LB) : N;
        int dlA  = (idxA < cnt) ? (int)(pkA & (BKN - 1)) : 0;
        int srcB = (idxB < cnt) ? (int)(pkB >> LB) : N;
        int dlB  = (idxB < cnt) ? (int)(pkB & (BKN - 1)) : 0;
        uint4 uA = *(const uint4*)(hsrc + (size_t)srcA * 64);
        uint4 uB = *(const uint4*)(hsrc + (size_t)srcB * 64);
        float* apA = acc + dlA * 72;
        float* apB = acc + dlB * 72;
        ATOM(apA, uA)
        ATOM(apB, uB)
    }
#undef ATOM
    __syncthreads();

    // epilogue: 2 threads per row, 32 feats each
    int row = tid >> 1;
    int half = (tid & 1) * 32;
    int node = (b << LB) + row;
    if (node >= N) return;
    float sc = dinv[node];
    int h8 = (tid & 1) * 4;              // octet base for this half
#pragma unroll
    for (int q = 0; q < 4; q++) {
        int f = half + q * 8;
        uint4 sv = *(const uint4*)(hs + (size_t)node * 64 + f);
        float4 bv0 = *(const float4*)(bias + f);
        float4 bv1 = *(const float4*)(bias + f + 4);
        int oc = h8 + q;                 // stored octet column
        float o0 = sc * (acc[row * 72 + 0 * 8 + oc] + bflo(sv.x)) + bv0.x;
        float o1 = sc * (acc[row * 72 + 1 * 8 + oc] + bfhi(sv.x)) + bv0.y;
        float o2 = sc * (acc[row * 72 + 2 * 8 + oc] + bflo(sv.y)) + bv0.z;
        float o3 = sc * (acc[row * 72 + 3 * 8 + oc] + bfhi(sv.y)) + bv0.w;
        float o4 = sc * (acc[row * 72 + 4 * 8 + oc] + bflo(sv.z)) + bv1.x;
        float o5 = sc * (acc[row * 72 + 5 * 8 + oc] + bfhi(sv.z)) + bv1.y;
        float o6 = sc * (acc[row * 72 + 6 * 8 + oc] + bflo(sv.w)) + bv1.z;
        float o7 = sc * (acc[row * 72 + 7 * 8 + oc] + bfhi(sv.w)) + bv1.w;
        if (RELU) {
            o0 = fmaxf(o0, 0.f); o1 = fmaxf(o1, 0.f);
            o2 = fmaxf(o2, 0.f); o3 = fmaxf(o3, 0.f);
            o4 = fmaxf(o4, 0.f); o5 = fmaxf(o5, 0.f);
            o6 = fmaxf(o6, 0.f); o7 = fmaxf(o7, 0.f);
        }
        if (F32OUT) {
            uint4 rb = *(const uint4*)(residb + (size_t)node * 64 + f);
            o0 += bflo(rb.x); o1 += bfhi(rb.x);
            o2 += bflo(rb.y); o3 += bfhi(rb.y);
            o4 += bflo(rb.z); o5 += bfhi(rb.z);
            o6 += bflo(rb.w); o7 += bfhi(rb.w);
            float* op = outf + (size_t)node * 64 + f;
            *(float4*)op = make_float4(o0, o1, o2, o3);
            *(float4*)(op + 4) = make_float4(o4, o5, o6, o7);
        } else {
            unsigned w0 = f2bf(o0) | (f2bf(o1) << 16);
            unsigned w1 = f2bf(o2) | (f2bf(o3) << 16);
            unsigned w2 = f2bf(o4) | (f2bf(o5) << 16);
            unsigned w3 = f2bf(o6) | (f2bf(o7) << 16);
            *(uint4*)(outb + (size_t)node * 64 + f) = make_uint4(w0, w1, w2, w3);
        }
    }
}

// ---------------------------------------------------------------------------
extern "C" void kernel_launch(void* const* d_in, const int* in_sizes, int n_in,
                              void* d_out, int out_size, void* d_ws, size_t ws_size,
                              hipStream_t stream) {
    const float* x  = (const float*)d_in[0];
    const int*   ei = (const int*)d_in[1];
    const float* W0 = (const float*)d_in[2];
    const float* b0 = (const float*)d_in[3];
    const float* Ws = (const float*)d_in[4];
    const float* bs = (const float*)d_in[5];
    float* out = (float*)d_out;

    const int N = in_sizes[0] / 128;
    const int E = in_sizes[1] / 2;
    const int B = (N + BKN - 1) >> LB;

    char* p = (char*)d_ws;
    auto carve = [&](size_t bytes) {
        char* r = p;
        p += (bytes + 255) & ~(size_t)255;
        return r;
    };
    int*      bucketCursor = (int*)carve(1024 * 4);
    unsigned* packed       = (unsigned*)carve(((size_t)B * CAP + 64) * 4); // +slack
    float*    dinv         = (float*)carve((size_t)N * 4);
    ushort_t* hs           = (ushort_t*)carve((size_t)(N + 1) * 64 * 2);   // +sentinel
    ushort_t* xtb          = (ushort_t*)carve((size_t)N * 64 * 2);
    ushort_t* hb           = (ushort_t*)carve((size_t)N * 64 * 2);

    hipMemsetAsync(bucketCursor, 0, 1024 * 4, stream);

    k_scatter<<<(E + CHUNK - 1) / CHUNK, 256, 0, stream>>>(ei, E, bucketCursor, packed);
    k_dinv<<<B, 256, 0, stream>>>(packed, bucketCursor, dinv, hs, N);

    int gb = (N + 127) / 128;

    // layer 1: hs = (x @ W0) * dinv ; agg1 -> xtb (bf16, +b0, no relu)
    k_gemm1<<<gb, 256, 0, stream>>>(x, W0, dinv, hs, N);
    k_aggbkt<0, 0><<<B, 256, 0, stream>>>(hs, dinv, b0, packed, bucketCursor,
                                          nullptr, nullptr, xtb, N);
    // layer 2: hs = (xtb @ Ws0) * dinv ; agg2 -> hb (bf16, +bs0, relu)
    k_gemm64<<<gb, 256, 0, stream>>>(xtb, Ws, dinv, hs, N);
    k_aggbkt<1, 0><<<B, 256, 0, stream>>>(hs, dinv, bs, packed, bucketCursor,
                                          nullptr, nullptr, hb, N);
    // layer 3: hs = (hb @ Ws1) * dinv ; agg3 -> out (f32, +bs1, relu, +resid)
    k_gemm64<<<gb, 256, 0, stream>>>(hb, Ws + 64 * 64, dinv, hs, N);
    k_aggbkt<1, 1><<<B, 256, 0, stream>>>(hs, dinv, bs + 64, packed, bucketCursor,
                                          xtb, out, nullptr, N);
}

// Round 10
// 284.458 us; speedup vs baseline: 7.7450x; 7.7450x over previous
//
#include <hip/hip_runtime.h>

// ---------------------------------------------------------------------------
// GCN block: 3x (MFMA bf16 GEMM -> degree-normalized aggregate), resid, relu.
// 9 dispatches: memset(cursors) | scatter(fixed-CAP buckets) |
//   sort(+pad,+dinv,+rp2) | gemm1 | agg1 | gemm2 | agg2 | gemm3 | agg3
// R22: REVERT to R19 agg (best: 288.1us) + R20 single-pass sort, after R21's
// edge-parallel LDS-accum agg failed at 685us (2 gathers in flight vs ~11,
// 4 blocks/CU from 36.9KB LDS => outstanding lines/CU 120->30; agg is MLP x
// random-line-service bound, ~43.5us is the floor, confirmed from both
// sides). New micro-opts this round:
//  * k_scatter: ei loads vectorized -- 4 edges per uint4 pair (alignment-
//    guarded, scalar fallback), halves load instruction count.
//  * k_sort: shfl_up wave scan + 1-barrier combine replaces the 16-barrier
//    LDS Hillis-Steele ladder.
// R20: single-pass sort (SEPT regs, fallback). R19: issue-all-then-accum
// tiered agg. R16: single-pass scatter. R15 lesson: direct CSR fill = 104MB
// write amp. R14: direct col loads. R10: no barrier-coupled gather fusion.
// R9: dinv in GEMM epilogue.
// ---------------------------------------------------------------------------

#define LB 8
#define BKN 256
#define CHUNK 4096
#define EPT 16                     // edges per thread in scatter (CHUNK/256)
#define SEPT 20                    // packed entries per thread in sort regs
#define CAP 8192                   // packed slots per bucket (mean fill 4092)
#define PADS 3                     // segment padding to x4
#define CAPCOL (CAP + BKN * PADS)  // padded col region per bucket

typedef unsigned short ushort_t;
typedef __attribute__((ext_vector_type(8))) short bf16x8;
typedef __attribute__((ext_vector_type(4))) float f32x4;

__device__ __forceinline__ unsigned f2bf(float f) {
    unsigned u = __builtin_bit_cast(unsigned, f);
    return (u + 0x7FFFu + ((u >> 16) & 1u)) >> 16;   // RNE
}
__device__ __forceinline__ float bflo(unsigned u) {
    return __builtin_bit_cast(float, u << 16);
}
__device__ __forceinline__ float bfhi(unsigned u) {
    return __builtin_bit_cast(float, u & 0xFFFF0000u);
}

// per-block int64-vs-int32 probe (sampled; same result in every block)
__device__ int detect_f64(const int* ei, int E, int* sflag) {
    if (threadIdx.x == 0) *sflag = 0;
    __syncthreads();
    const unsigned* raw = (const unsigned*)ei;
    int dwords = min(2 * E, 512);
    int any = 0;
    for (int i = threadIdx.x; i < dwords; i += blockDim.x)
        if ((i & 1) && raw[i]) any = 1;
    if (any) atomicOr(sflag, 1);
    __syncthreads();
    return !*sflag;   // all sampled high words zero => int64
}

// ---- scatter: partition edges into fixed-CAP bucket regions ---------------
// packed[b*CAP + cursor] = (src<<8 | dst&255); cursor is RELATIVE (0-init).
// Single pass over ei, 4 edges per uint4 load pair (alignment-guarded).
__global__ __launch_bounds__(256) void k_scatter(
        const int* __restrict__ ei, int E,
        int* __restrict__ bucketCursor, unsigned int* __restrict__ packed) {
    __shared__ int hist[512];
    __shared__ int base[512];
    __shared__ int sflag;
    int f64 = detect_f64(ei, E, &sflag);
    int b0 = blockIdx.x * CHUNK;
    int n = min(CHUNK, E - b0);
    int tid = threadIdx.x;
    for (int i = tid; i < 512; i += 256) hist[i] = 0;
    __syncthreads();
    int dreg[EPT], sreg[EPT];
    // vectorization valid only if dst-array base stays 16B-aligned
    bool vec_ok = f64 ? ((E & 1) == 0) : ((E & 3) == 0);
    if (vec_ok) {
#pragma unroll
        for (int j = 0; j < EPT / 4; j++) {
            int idx = tid * 4 + j * 1024;     // blocked mapping, 16B-aligned
            if (idx + 3 < n) {
                int e = b0 + idx;
                if (f64) {
                    uint4 sa = *(const uint4*)(ei + 2 * (size_t)e);
                    uint4 sb = *(const uint4*)(ei + 2 * (size_t)e + 4);
                    uint4 da = *(const uint4*)(ei + 2 * ((size_t)E + e));
                    uint4 db = *(const uint4*)(ei + 2 * ((size_t)E + e) + 4);
                    sreg[j * 4 + 0] = (int)sa.x; sreg[j * 4 + 1] = (int)sa.z;
                    sreg[j * 4 + 2] = (int)sb.x; sreg[j * 4 + 3] = (int)sb.z;
                    dreg[j * 4 + 0] = (int)da.x; dreg[j * 4 + 1] = (int)da.z;
                    dreg[j * 4 + 2] = (int)db.x; dreg[j * 4 + 3] = (int)db.z;
                } else {
                    uint4 sv = *(const uint4*)(ei + e);
                    uint4 dv = *(const uint4*)(ei + E + e);
                    sreg[j * 4 + 0] = (int)sv.x; sreg[j * 4 + 1] = (int)sv.y;
                    sreg[j * 4 + 2] = (int)sv.z; sreg[j * 4 + 3] = (int)sv.w;
                    dreg[j * 4 + 0] = (int)dv.x; dreg[j * 4 + 1] = (int)dv.y;
                    dreg[j * 4 + 2] = (int)dv.z; dreg[j * 4 + 3] = (int)dv.w;
                }
            } else {
#pragma unroll
                for (int k = 0; k < 4; k++) {
                    int ii = idx + k;
                    if (ii < n) {
                        int e = b0 + ii;
                        dreg[j * 4 + k] = f64 ? ei[2 * (E + e)] : ei[E + e];
                        sreg[j * 4 + k] = f64 ? ei[2 * e] : ei[e];
                    } else {
                        dreg[j * 4 + k] = -1;   // invalid marker
                    }
                }
            }
        }
    } else {
#pragma unroll
        for (int i = 0; i < EPT; i++) {
            int idx = tid + i * 256;
            if (idx < n) {
                int e = b0 + idx;
                dreg[i] = f64 ? ei[2 * (E + e)] : ei[E + e];
                sreg[i] = f64 ? ei[2 * e] : ei[e];
            } else {
                dreg[i] = -1;
            }
        }
    }
#pragma unroll
    for (int i = 0; i < EPT; i++)
        if (dreg[i] >= 0) atomicAdd(&hist[dreg[i] >> LB], 1);
    __syncthreads();
    for (int i = tid; i < 512; i += 256) {
        int c = hist[i];
        base[i] = c ? atomicAdd(&bucketCursor[i], c) : 0;
        hist[i] = 0;
    }
    __syncthreads();
#pragma unroll
    for (int i = 0; i < EPT; i++) {
        if (dreg[i] >= 0) {
            int bk = dreg[i] >> LB;
            int pos = bk * CAP + base[bk] + atomicAdd(&hist[bk], 1);
            packed[pos] = ((unsigned)sreg[i] << LB) | (unsigned)(dreg[i] & (BKN - 1));
        }
    }
}

// ---- per-bucket counting sort -> padded CSR col[], rp2, dinv --------------
// Bucket b's packed region: [b*CAP, b*CAP + cnt). Single global read: each
// thread keeps SEPT entries in regs (hist + fill from regs); fallback to
// re-read if cnt > 256*SEPT (mean 4092, 16 sigma -- practically never).
// Scan: shfl_up wave scan + 1-barrier cross-wave combine (was 16 barriers).
// Node segments padded to x4 with sentinel index N; hs row N zeroed here.
__global__ __launch_bounds__(256) void k_sort(
        const unsigned int* __restrict__ packed, const int* __restrict__ bucketCursor,
        int* __restrict__ col, int2* __restrict__ rp2, float* __restrict__ dinv,
        ushort_t* __restrict__ hs, int N) {
    __shared__ int hist[BKN];
    __shared__ int cur[BKN];
    __shared__ int wtot[4];
    int tid = threadIdx.x;
    int b = blockIdx.x;
    int start = b * CAP;
    int cnt = bucketCursor[b];
    int end = start + cnt;
    int inreg = (cnt <= 256 * SEPT);
    unsigned preg[SEPT];
    hist[tid] = 0;
    __syncthreads();
    if (inreg) {
#pragma unroll
        for (int i = 0; i < SEPT; i++) {
            int e = start + tid + i * 256;
            if (e < end) {
                preg[i] = packed[e];
                atomicAdd(&hist[preg[i] & (BKN - 1)], 1);
            }
        }
    } else {
        for (int e = start + tid; e < end; e += 256)
            atomicAdd(&hist[packed[e] & (BKN - 1)], 1);
    }
    __syncthreads();
    int v = hist[tid];
    int pv = (v + PADS) & ~PADS;        // padded length (x4)
    // inclusive scan of pv over 256 threads: wave shfl scan + combine
    int lane = tid & 63, wid = tid >> 6;
    int sc = pv;
#pragma unroll
    for (int off = 1; off < 64; off <<= 1) {
        int x = __shfl_up(sc, off);
        if (lane >= off) sc += x;
    }
    if (lane == 63) wtot[wid] = sc;
    __syncthreads();
    int add = 0;
#pragma unroll
    for (int w2 = 0; w2 < 3; w2++)
        if (wid > w2) add += wtot[w2];
    int excl = sc + add - pv;           // exclusive prefix within bucket
    int st = b * CAPCOL + excl;         // padded col base, buckets disjoint
    cur[tid] = st;
    int node = (b << LB) + tid;
    if (node < N) {
        rp2[node] = make_int2(st, st + pv);
        dinv[node] = rsqrtf((float)(v + 1));   // +1 self loop
        for (int i = v; i < pv; i++) col[st + i] = N;   // sentinel padding
    }
    if (b == 0 && tid < 64) hs[(size_t)N * 64 + tid] = 0;   // zero row N
    __syncthreads();
    if (inreg) {
#pragma unroll
        for (int i = 0; i < SEPT; i++) {
            int e = start + tid + i * 256;
            if (e < end) {
                unsigned pvk = preg[i];
                int pos = atomicAdd(&cur[pvk & (BKN - 1)], 1);
                col[pos] = (int)(pvk >> LB);
            }
        }
    } else {
        for (int e = start + tid; e < end; e += 256) {
            unsigned pvk = packed[e];
            int pos = atomicAdd(&cur[pvk & (BKN - 1)], 1);
            col[pos] = (int)(pvk >> LB);
        }
    }
}

// ---- gemm1: (N x 128) @ (128 x 64), f32 in, dinv-scaled, bf16 out ---------
__global__ __launch_bounds__(256) void k_gemm1(
        const float* __restrict__ A, const float* __restrict__ W,
        const float* __restrict__ dinv, ushort_t* __restrict__ out, int nrows) {
    const int K = 128;
    __shared__ ushort_t sWT[64 * (K + 8)];
    int tid = threadIdx.x;
    for (int i = tid; i < K * 64; i += 256) {
        int n = i & 63, k = i >> 6;
        sWT[n * (K + 8) + k] = (ushort_t)f2bf(W[i]);
    }
    __syncthreads();
    int wave = tid >> 6, lane = tid & 63;
    int quad = lane >> 4, l16 = lane & 15;
    int rowBase = blockIdx.x * 128 + wave * 32;
    f32x4 acc[2][4];
#pragma unroll
    for (int r = 0; r < 2; r++)
#pragma unroll
        for (int c = 0; c < 4; c++) acc[r][c] = (f32x4){0.f, 0.f, 0.f, 0.f};
#pragma unroll
    for (int chunk = 0; chunk < K / 32; chunk++) {
        bf16x8 afr[2];
#pragma unroll
        for (int r = 0; r < 2; r++) {
            int row = rowBase + r * 16 + l16;
            if (row >= nrows) row = nrows - 1;
            const float* ap = A + (size_t)row * K + chunk * 32 + quad * 8;
            float4 v0 = *(const float4*)ap;
            float4 v1 = *(const float4*)(ap + 4);
            bf16x8 a;
            a[0] = (short)f2bf(v0.x); a[1] = (short)f2bf(v0.y);
            a[2] = (short)f2bf(v0.z); a[3] = (short)f2bf(v0.w);
            a[4] = (short)f2bf(v1.x); a[5] = (short)f2bf(v1.y);
            a[6] = (short)f2bf(v1.z); a[7] = (short)f2bf(v1.w);
            afr[r] = a;
        }
#pragma unroll
        for (int c = 0; c < 4; c++) {
            bf16x8 bfr = __builtin_bit_cast(
                bf16x8,
                *(const uint4*)&sWT[(c * 16 + l16) * (K + 8) + chunk * 32 + quad * 8]);
#pragma unroll
            for (int r = 0; r < 2; r++)
                acc[r][c] = __builtin_amdgcn_mfma_f32_16x16x32_bf16(
                    afr[r], bfr, acc[r][c], 0, 0, 0);
        }
    }
#pragma unroll
    for (int r = 0; r < 2; r++)
#pragma unroll
        for (int i = 0; i < 4; i++) {
            int row = rowBase + r * 16 + quad * 4 + i;
            if (row < nrows) {
                float sc = dinv[row];
#pragma unroll
                for (int c = 0; c < 4; c++)
                    out[(size_t)row * 64 + c * 16 + l16] =
                        (ushort_t)f2bf(acc[r][c][i] * sc);
            }
        }
}

// ---- gemm64: (N x 64) @ (64 x 64), bf16 in, dinv-scaled, bf16 out ---------
__global__ __launch_bounds__(256) void k_gemm64(
        const ushort_t* __restrict__ A, const float* __restrict__ W,
        const float* __restrict__ dinv, ushort_t* __restrict__ out, int nrows) {
    const int K = 64;
    __shared__ ushort_t sWT[64 * (K + 8)];
    int tid = threadIdx.x;
    for (int i = tid; i < K * 64; i += 256) {
        int n = i & 63, k = i >> 6;
        sWT[n * (K + 8) + k] = (ushort_t)f2bf(W[i]);
    }
    __syncthreads();
    int wave = tid >> 6, lane = tid & 63;
    int quad = lane >> 4, l16 = lane & 15;
    int rowBase = blockIdx.x * 128 + wave * 32;
    f32x4 acc[2][4];
#pragma unroll
    for (int r = 0; r < 2; r++)
#pragma unroll
        for (int c = 0; c < 4; c++) acc[r][c] = (f32x4){0.f, 0.f, 0.f, 0.f};
#pragma unroll
    for (int chunk = 0; chunk < K / 32; chunk++) {
        bf16x8 afr[2];
#pragma unroll
        for (int r = 0; r < 2; r++) {
            int row = rowBase + r * 16 + l16;
            if (row >= nrows) row = nrows - 1;
            const ushort_t* ap = A + (size_t)row * K + chunk * 32 + quad * 8;
            afr[r] = __builtin_bit_cast(bf16x8, *(const uint4*)ap);
        }
#pragma unroll
        for (int c = 0; c < 4; c++) {
            bf16x8 bfr = __builtin_bit_cast(
                bf16x8,
                *(const uint4*)&sWT[(c * 16 + l16) * (K + 8) + chunk * 32 + quad * 8]);
#pragma unroll
            for (int r = 0; r < 2; r++)
                acc[r][c] = __builtin_amdgcn_mfma_f32_16x16x32_bf16(
                    afr[r], bfr, acc[r][c], 0, 0, 0);
        }
    }
#pragma unroll
    for (int r = 0; r < 2; r++)
#pragma unroll
        for (int i = 0; i < 4; i++) {
            int row = rowBase + r * 16 + quad * 4 + i;
            if (row < nrows) {
                float sc = dinv[row];
#pragma unroll
                for (int c = 0; c < 4; c++)
                    out[(size_t)row * 64 + c * 16 + l16] =
                        (ushort_t)f2bf(acc[r][c][i] * sc);
            }
        }
}

// ---- aggregation: ONE node per wave, issue-all-then-accumulate ------------
// Row = 64 bf16 = 128B = 16 lanes x uint2. Lane group g = lane>>4 owns edge
// slot 4j+g. Wave-uniform degree tiers: pv<=16 -> 4 col + 4 gathers batched,
// single wait, accumulate; pv<=32 -> 8+8 batched; pv>32 (P~2e-4) -> unmasked
// 32-bursts then masked tail. Slots >= pv map to sentinel row N (zeros,
// L1-hot); col overreads stay inside the +guard region. rp2/self/dinv issue
// up-front in parallel. Cross-group reduce shfl_xor(16/32); lanes 0-15 write.
template <int RELU, int F32OUT>
__global__ __launch_bounds__(256) void k_aggb(
        const ushort_t* __restrict__ hs, const float* __restrict__ dinv,
        const float* __restrict__ bias, const int* __restrict__ col,
        const int2* __restrict__ rp2, const ushort_t* __restrict__ residb,
        float* __restrict__ outf, ushort_t* __restrict__ outb, int n) {
    int node = (int)((blockIdx.x * blockDim.x + threadIdx.x) >> 6);
    if (node >= n) return;
    int lane = threadIdx.x & 63;
    int g = lane >> 4;                   // edge sub-slot within a 16-batch
    int c4 = lane & 15;                  // feature group: cols c4*4..c4*4+3
    const ushort_t* hrow = hs + (size_t)c4 * 4;
    // independent loads first: self row, dinv, then rp2 (all in flight)
    uint2 us = *(const uint2*)(hs + (size_t)node * 64 + c4 * 4);  // self loop
    float sc = dinv[node];
    int2 r = rp2[node];
    int e = r.x, p = r.y;                // p-e multiple of 4
    float a0 = 0.f, a1 = 0.f, a2 = 0.f, a3 = 0.f;

#define GR(m) (*(const uint2*)(hrow + (size_t)(m) * 64))
#define GACC(u)                                                             \
    a0 += bflo(u.x); a1 += bfhi(u.x);                                       \
    a2 += bflo(u.y); a3 += bfhi(u.y);

    while (p - e > 32) {                 // rare (P(deg>32) ~ 2e-4)
        int m0 = col[e + g],      m1 = col[e + 4 + g];
        int m2 = col[e + 8 + g],  m3 = col[e + 12 + g];
        int m4 = col[e + 16 + g], m5 = col[e + 20 + g];
        int m6 = col[e + 24 + g], m7 = col[e + 28 + g];
        uint2 u0 = GR(m0), u1 = GR(m1), u2 = GR(m2), u3 = GR(m3);
        uint2 u4 = GR(m4), u5 = GR(m5), u6 = GR(m6), u7 = GR(m7);
        GACC(u0) GACC(u1) GACC(u2) GACC(u3)
        GACC(u4) GACC(u5) GACC(u6) GACC(u7)
        e += 32;
    }
    int rem = p - e;                     // 0..32, multiple of 4
    if (rem > 16) {
        // slots 0..15 all valid (rem >= 20); slots 16..31 masked
        int c0 = col[e + g],      c1 = col[e + 4 + g];
        int c2 = col[e + 8 + g],  c3 = col[e + 12 + g];
        int c5 = col[e + 16 + g], c6 = col[e + 20 + g];
        int c7 = col[e + 24 + g], c8 = col[e + 28 + g];
        int m4 = (16 + g < rem) ? c5 : n;
        int m5 = (20 + g < rem) ? c6 : n;
        int m6 = (24 + g < rem) ? c7 : n;
        int m7 = (28 + g < rem) ? c8 : n;
        uint2 u0 = GR(c0), u1 = GR(c1), u2 = GR(c2), u3 = GR(c3);
        uint2 u4 = GR(m4), u5 = GR(m5), u6 = GR(m6), u7 = GR(m7);
        GACC(u0) GACC(u1) GACC(u2) GACC(u3)
        GACC(u4) GACC(u5) GACC(u6) GACC(u7)
    } else if (rem > 0) {
        int c0 = col[e + g],     c1 = col[e + 4 + g];
        int c2 = col[e + 8 + g], c3 = col[e + 12 + g];
        int m0 = (g < rem)      ? c0 : n;
        int m1 = (4 + g < rem)  ? c1 : n;
        int m2 = (8 + g < rem)  ? c2 : n;
        int m3 = (12 + g < rem) ? c3 : n;
        uint2 u0 = GR(m0), u1 = GR(m1), u2 = GR(m2), u3 = GR(m3);
        GACC(u0) GACC(u1) GACC(u2) GACC(u3)
    }
#undef GR
#undef GACC

    a0 += __shfl_xor(a0, 16); a0 += __shfl_xor(a0, 32);
    a1 += __shfl_xor(a1, 16); a1 += __shfl_xor(a1, 32);
    a2 += __shfl_xor(a2, 16); a2 += __shfl_xor(a2, 32);
    a3 += __shfl_xor(a3, 16); a3 += __shfl_xor(a3, 32);

    if (lane < 16) {
        a0 += bflo(us.x); a1 += bfhi(us.x);
        a2 += bflo(us.y); a3 += bfhi(us.y);
        float4 bv = *(const float4*)(bias + c4 * 4);
        float o0 = sc * a0 + bv.x, o1 = sc * a1 + bv.y;
        float o2 = sc * a2 + bv.z, o3 = sc * a3 + bv.w;
        if (RELU) {
            o0 = fmaxf(o0, 0.f); o1 = fmaxf(o1, 0.f);
            o2 = fmaxf(o2, 0.f); o3 = fmaxf(o3, 0.f);
        }
        if (F32OUT) {
            uint2 rb = *(const uint2*)(residb + (size_t)node * 64 + c4 * 4);
            o0 += bflo(rb.x); o1 += bfhi(rb.x);
            o2 += bflo(rb.y); o3 += bfhi(rb.y);
            *(float4*)(outf + (size_t)node * 64 + c4 * 4) =
                make_float4(o0, o1, o2, o3);
        } else {
            unsigned w0 = f2bf(o0) | (f2bf(o1) << 16);
            unsigned w1 = f2bf(o2) | (f2bf(o3) << 16);
            *(uint2*)(outb + (size_t)node * 64 + c4 * 4) = make_uint2(w0, w1);
        }
    }
}

// ---------------------------------------------------------------------------
extern "C" void kernel_launch(void* const* d_in, const int* in_sizes, int n_in,
                              void* d_out, int out_size, void* d_ws, size_t ws_size,
                              hipStream_t stream) {
    const float* x  = (const float*)d_in[0];
    const int*   ei = (const int*)d_in[1];
    const float* W0 = (const float*)d_in[2];
    const float* b0 = (const float*)d_in[3];
    const float* Ws = (const float*)d_in[4];
    const float* bs = (const float*)d_in[5];
    float* out = (float*)d_out;

    const int N = in_sizes[0] / 128;
    const int E = in_sizes[1] / 2;
    const int B = (N + BKN - 1) >> LB;

    char* p = (char*)d_ws;
    auto carve = [&](size_t bytes) {
        char* r = p;
        p += (bytes + 255) & ~(size_t)255;
        return r;
    };
    int*      bucketCursor = (int*)carve(512 * 4);
    unsigned* packed       = (unsigned*)carve((size_t)B * CAP * 4);
    int*      col          = (int*)carve(((size_t)B * CAPCOL + 64) * 4);  // +guard
    int2*     rp2          = (int2*)carve((size_t)N * 8);
    float*    dinv         = (float*)carve((size_t)N * 4);
    ushort_t* hs           = (ushort_t*)carve((size_t)(N + 1) * 64 * 2); // +sentinel
    ushort_t* xtb          = (ushort_t*)carve((size_t)N * 64 * 2);
    ushort_t* hb           = (ushort_t*)carve((size_t)N * 64 * 2);

    hipMemsetAsync(bucketCursor, 0, 512 * 4, stream);

    k_scatter<<<(E + CHUNK - 1) / CHUNK, 256, 0, stream>>>(ei, E, bucketCursor, packed);
    k_sort<<<B, 256, 0, stream>>>(packed, bucketCursor, col, rp2, dinv, hs, N);

    int gb = (N + 127) / 128;
    int ablocks = (N + 3) / 4;   // 1 node/wave, 4 waves/block

    // layer 1: hs = (x @ W0) * dinv ; agg1 -> xtb (bf16, +b0, no relu)
    k_gemm1<<<gb, 256, 0, stream>>>(x, W0, dinv, hs, N);
    k_aggb<0, 0><<<ablocks, 256, 0, stream>>>(hs, dinv, b0, col, rp2,
                                              nullptr, nullptr, xtb, N);
    // layer 2: hs = (xtb @ Ws0) * dinv ; agg2 -> hb (bf16, +bs0, relu)
    k_gemm64<<<gb, 256, 0, stream>>>(xtb, Ws, dinv, hs, N);
    k_aggb<1, 0><<<ablocks, 256, 0, stream>>>(hs, dinv, bs, col, rp2,
                                              nullptr, nullptr, hb, N);
    // layer 3: hs = (hb @ Ws1) * dinv ; agg3 -> out (f32, +bs1, relu, +resid)
    k_gemm64<<<gb, 256, 0, stream>>>(hb, Ws + 64 * 64, dinv, hs, N);
    k_aggb<1, 1><<<ablocks, 256, 0, stream>>>(hs, dinv, bs + 64, col, rp2,
                                              xtb, out, nullptr, N);
}